// Round 8
// baseline (519.816 us; speedup 1.0000x reference)
//
#include <hip/hip_runtime.h>
#include <hip/hip_bf16.h>
#include <math.h>
#include <stdint.h>

#define BT  4096
#define DIM 1024
#define HID 4096
#define NE  8
#define TMX  72   // max active 128-row m-blocks (gemm2)
#define TMX2 40   // max active 256-row m-blocks (gemm1)

typedef __attribute__((ext_vector_type(8))) short short8v;
typedef __attribute__((ext_vector_type(4))) float f32x4;
typedef unsigned short ushort_t;

typedef __attribute__((address_space(1))) const void gas_void;
typedef __attribute__((address_space(3))) void las_void;
#define GLOAD_LDS16(g, l) __builtin_amdgcn_global_load_lds((gas_void*)(g), (las_void*)(l), 16, 0, 0)

__device__ inline ushort_t f2bf(float f) {
  __hip_bfloat16 b = __float2bfloat16(f);
  union { __hip_bfloat16 h; ushort_t u; } cv;
  cv.h = b;
  return cv.u;
}

// -------- fused prep + router: one block per token --------
__global__ __launch_bounds__(256) void k_prep_router(
    const float* __restrict__ x, const float* __restrict__ wg,
    ushort_t* __restrict__ xbf, float* __restrict__ logits_out,
    float* __restrict__ probs01, int* __restrict__ assign,
    int* __restrict__ cur) {
  int t = blockIdx.x;
  int tid = threadIdx.x;
  const float* xr = x + (size_t)t * DIM;
  float4 v = ((const float4*)xr)[tid];
  ushort4 o;
  o.x = f2bf(v.x); o.y = f2bf(v.y); o.z = f2bf(v.z); o.w = f2bf(v.w);
  ((ushort4*)(xbf + (size_t)t * DIM))[tid] = o;

  float vv[4] = {v.x, v.y, v.z, v.w};
  float part[NE];
#pragma unroll
  for (int e = 0; e < NE; e++) part[e] = 0.f;
#pragma unroll
  for (int i = 0; i < 4; i++) {
    const float4* wr = (const float4*)(wg + (size_t)(tid * 4 + i) * NE);
    float4 a = wr[0], b = wr[1];
    part[0] += vv[i] * a.x; part[1] += vv[i] * a.y;
    part[2] += vv[i] * a.z; part[3] += vv[i] * a.w;
    part[4] += vv[i] * b.x; part[5] += vv[i] * b.y;
    part[6] += vv[i] * b.z; part[7] += vv[i] * b.w;
  }
#pragma unroll
  for (int e = 0; e < NE; e++)
    for (int off = 32; off > 0; off >>= 1)
      part[e] += __shfl_xor(part[e], off);

  __shared__ float red[4][NE];
  int lane = tid & 63, wv = tid >> 6;
  if (lane == 0) {
#pragma unroll
    for (int e = 0; e < NE; e++) red[wv][e] = part[e];
  }
  __syncthreads();
  if (tid == 0) {
    float s8[NE];
#pragma unroll
    for (int e = 0; e < NE; e++)
      s8[e] = red[0][e] + red[1][e] + red[2][e] + red[3][e];
    float m = s8[0];
    for (int e = 1; e < NE; e++) m = fmaxf(m, s8[e]);
    float p[NE], s = 0.f;
    for (int e = 0; e < NE; e++) { p[e] = expf(s8[e] - m); s += p[e]; }
    float inv = 1.f / s;
    for (int e = 0; e < NE; e++) p[e] *= inv;
    for (int e = 0; e < NE; e++) logits_out[(size_t)t * NE + e] = s8[e];
    probs01[t * 2 + 0] = p[0];
    probs01[t * 2 + 1] = p[1];
    int b0 = 0;
    for (int e = 1; e < NE; e++) if (p[e] > p[b0]) b0 = e;
    int b1 = (b0 == 0) ? 1 : 0;
    for (int e = 0; e < NE; e++) if (e != b0 && p[e] > p[b1]) b1 = e;
    int pos0 = atomicAdd(&cur[b0], 1);
    assign[b0 * BT + pos0] = t * 2 + 0;
    int pos1 = atomicAdd(&cur[b1], 1);
    assign[b1 * BT + pos1] = t * 2 + 1;
  }
}

// -------- plan: prefix offsets + both active block lists --------
__global__ void k_plan(const int* __restrict__ cur, int* __restrict__ segoff,
                       int* __restrict__ blk2_e, int* __restrict__ blk2_m0,
                       int* __restrict__ blk_e, int* __restrict__ blk_m0) {
  if (threadIdx.x == 0 && blockIdx.x == 0) {
    int s = 0;
    for (int e = 0; e < NE; e++) { segoff[e] = s; s += cur[e]; }
    int t = 0;
    for (int e = 0; e < NE; e++) {
      int mb = (cur[e] + 255) >> 8;
      for (int i = 0; i < mb; i++) { blk2_e[t] = e; blk2_m0[t] = i << 8; t++; }
    }
    for (; t < TMX2; t++) { blk2_e[t] = -1; blk2_m0[t] = 0; }
    t = 0;
    for (int e = 0; e < NE; e++) {
      int mb = (cur[e] + 127) >> 7;
      for (int i = 0; i < mb; i++) { blk_e[t] = e; blk_m0[t] = i << 7; t++; }
    }
    for (; t < TMX; t++) { blk_e[t] = -1; blk_m0[t] = 0; }
  }
}

// ============================================================================
// Fused-transpose GEMMs.  B is staged straight from fp32 [k][n] weights:
// per thread 2 LDS units x 8 strided dword loads (lane-contiguous n ->
// coalesced 256B, L2-resident panel), cvt to bf16, 1 ds_write_b128/unit into
// the SAME swizzled [n][k] layout the verified read path consumes
// (write unit ko ^ ((n>>1)&3) == read unit g ^ ((lr>>1)&3)).
// T14 split: B(t+2) loads issued in tile t, drained+written in tile t+1.
// vmcnt ledger per thread per tile: A gload_lds = 2, B dword = 16 (in-order).
// Steady outstanding before drain: A(t+2)2,B(t+1)16,A(t+3)2,B(t+2)16 = 36;
// vmcnt(18) drains through B(t+1).  Prologue 16; tail 16, 0.
// ds_writes published by lgkmcnt(0) before each barrier.  Ring-4, single
// barrier per K-tile (R6 discipline, 3x harness-verified).
// ============================================================================
#define VM18 asm volatile("s_waitcnt vmcnt(18)" ::: "memory")
#define VM16 asm volatile("s_waitcnt vmcnt(16)" ::: "memory")
#define VM0  asm volatile("s_waitcnt vmcnt(0)" ::: "memory")
#define VMN  do {} while (0)
#define LGKM0 asm volatile("s_waitcnt lgkmcnt(0)" ::: "memory")

// ============================================================================
// GEMM1: h = gelu(x_gathered @ w1^T + b1).  256x256, BK=32, 512 thr (8 waves
// 2Mx4N, wave tile 128x64, acc[8][4]).  Grid 16*TMX2 = 640.
// ============================================================================
__global__ __launch_bounds__(512, 2) void k_gemm1(
    const ushort_t* __restrict__ xbf, const float* __restrict__ w1,
    const float* __restrict__ b1,
    const int* __restrict__ assign, const int* __restrict__ cur,
    const int* __restrict__ segoff, const int* __restrict__ blk2_e,
    const int* __restrict__ blk2_m0, ushort_t* __restrict__ hbuf) {
  const int nwg = 16 * TMX2;                   // 640
  int f = blockIdx.x;
  int lg = (f & 7) * (nwg >> 3) + (f >> 3);    // XCD chunk swizzle (bijective)
  int m_idx = lg % TMX2;                       // m-inner: chunk reuses B-panels
  int n_idx = lg / TMX2;
  int e = blk2_e[m_idx];
  if (e < 0) return;
  int m0 = blk2_m0[m_idx];
  int count = cur[e];
  int n0 = n_idx << 8;

  __shared__ __attribute__((aligned(16))) ushort_t A[4][256][32];
  __shared__ __attribute__((aligned(16))) ushort_t Bv[4][256][32];
  int tid = threadIdx.x;
  int lane = tid & 63, wid = tid >> 6;

  // A staging (gload_lds, bf16, gathered tokens) — unchanged from R6
  int srow = lane >> 2;
  int sunit = ((lane & 3) ^ ((lane >> 3) & 3)) << 3;
  int pA0 = m0 + wid * 16 + srow;
  int pA1 = pA0 + 128;
  int tok0 = (pA0 < count) ? (assign[e * BT + pA0] >> 1) : 0;
  int tok1 = (pA1 < count) ? (assign[e * BT + pA1] >> 1) : 0;
  const ushort_t* gA0 = xbf + (size_t)tok0 * DIM + sunit;
  const ushort_t* gA1 = xbf + (size_t)tok1 * DIM + sunit;

  // B staging (reg-transpose from fp32 w1 [D][H])
  int u0 = tid, u1 = tid + 512;
  int nu0 = u0 & 255, ko0 = u0 >> 8;
  int nu1 = u1 & 255, ko1 = u1 >> 8;
  int uo0 = ko0 ^ ((nu0 >> 1) & 3);
  int uo1 = ko1 ^ ((nu1 >> 1) & 3);
  const float* wbase = w1 + (size_t)e * DIM * HID;
  const float* gB0 = wbase + (size_t)(ko0 * 8) * HID + n0 + nu0;
  const float* gB1 = wbase + (size_t)(ko1 * 8) * HID + n0 + nu1;
  float brg[2][2][8];

  int wm = wid >> 2, wn = wid & 3;             // wave tile: 128(m) x 64(n)
  int lr = lane & 15, g = lane >> 4;
  int xsw = ((g ^ ((lr >> 1) & 3)) << 3);
  f32x4 acc[8][4];
  f32x4 zero = {0.f, 0.f, 0.f, 0.f};
#pragma unroll
  for (int m = 0; m < 8; m++)
#pragma unroll
    for (int n = 0; n < 4; n++) acc[m][n] = zero;

#define ALOAD1(SL, K0)                                         \
  { GLOAD_LDS16(gA0 + (K0), &A[SL][wid * 16][0]);              \
    GLOAD_LDS16(gA1 + (K0), &A[SL][128 + wid * 16][0]); }
#define BLOAD1(S, KT)                                                          \
  { const float* s0_ = gB0 + (size_t)(KT) * 32 * HID;                          \
    const float* s1_ = gB1 + (size_t)(KT) * 32 * HID;                          \
    _Pragma("unroll")                                                          \
    for (int j = 0; j < 8; j++) {                                              \
      brg[S][0][j] = s0_[(size_t)j * HID];                                     \
      brg[S][1][j] = s1_[(size_t)j * HID];                                     \
    } }
#define BWRITE1(S, SL)                                                         \
  { short8v p0_, p1_;                                                          \
    _Pragma("unroll")                                                          \
    for (int j = 0; j < 8; j++) {                                              \
      p0_[j] = (short)f2bf(brg[S][0][j]);                                      \
      p1_[j] = (short)f2bf(brg[S][1][j]);                                      \
    }                                                                          \
    *(short8v*)&Bv[SL][nu0][uo0 * 8] = p0_;                                    \
    *(short8v*)&Bv[SL][nu1][uo1 * 8] = p1_; }

#define TILEK1(SL, T, VMX, DOA, DOB, DOW, LS, WS)                               \
  { short8v bv[4], afl[4], afh[4];                                              \
    _Pragma("unroll")                                                           \
    for (int n = 0; n < 4; n++)                                                 \
      bv[n] = *(const short8v*)&Bv[SL][wn * 64 + n * 16 + lr][xsw];             \
    _Pragma("unroll")                                                           \
    for (int m = 0; m < 4; m++) {                                               \
      afl[m] = *(const short8v*)&A[SL][wm * 128 + m * 16 + lr][xsw];            \
      afh[m] = *(const short8v*)&A[SL][wm * 128 + 64 + m * 16 + lr][xsw];       \
    }                                                                           \
    if (DOA) { ALOAD1((((SL) + 3) & 3), ((T) + 3) * 32); }                      \
    if (DOB) { BLOAD1(LS, (T) + 2); }                                           \
    VMX;                                                                        \
    if (DOW) { BWRITE1(WS, (((SL) + 1) & 3)); }                                 \
    LGKM0;                                                                      \
    __builtin_amdgcn_s_barrier();                                               \
    __builtin_amdgcn_sched_barrier(0);                                          \
    __builtin_amdgcn_s_setprio(1);                                              \
    _Pragma("unroll")                                                           \
    for (int m = 0; m < 4; m++)                                                 \
      _Pragma("unroll")                                                         \
      for (int n = 0; n < 4; n++) {                                             \
        acc[m][n] = __builtin_amdgcn_mfma_f32_16x16x32_bf16(afl[m], bv[n],      \
                                                            acc[m][n], 0, 0, 0);\
        acc[4 + m][n] = __builtin_amdgcn_mfma_f32_16x16x32_bf16(afh[m], bv[n],  \
                                                        acc[4 + m][n], 0, 0, 0);\
      }                                                                         \
    __builtin_amdgcn_s_setprio(0); }

  // prologue: A slots 0-2 in flight; B(0),B(1) loaded; stage tile 0 fully
  ALOAD1(0, 0); ALOAD1(1, 32); ALOAD1(2, 64);
  BLOAD1(0, 0); BLOAD1(1, 1);
  VM16;                 // drain A0,A1,A2,B0 -> leave B1
  BWRITE1(0, 0);
  LGKM0;
  __builtin_amdgcn_s_barrier();
  __builtin_amdgcn_sched_barrier(0);

  const int NT = DIM / 32;                     // 32
  for (int t = 0; t < NT - 4; t += 4) {
    TILEK1(0, t + 0, VM18, 1, 1, 1, 0, 1);
    TILEK1(1, t + 1, VM18, 1, 1, 1, 1, 0);
    TILEK1(2, t + 2, VM18, 1, 1, 1, 0, 1);
    TILEK1(3, t + 3, VM18, 1, 1, 1, 1, 0);
  }
  TILEK1(0, NT - 4, VM18, 1, 1, 1, 0, 1);
  TILEK1(1, NT - 3, VM16, 0, 1, 1, 1, 0);
  TILEK1(2, NT - 2, VM0,  0, 0, 1, 0, 1);
  TILEK1(3, NT - 1, VMN,  0, 0, 0, 0, 0);
#undef ALOAD1
#undef BLOAD1
#undef BWRITE1
#undef TILEK1

  int so = segoff[e];
#pragma unroll
  for (int m = 0; m < 8; m++) {
#pragma unroll
    for (int j = 0; j < 4; j++) {
      int p = m0 + wm * 128 + m * 16 + g * 4 + j;
      if (p >= count) continue;
      ushort_t* hr = hbuf + (size_t)(so + p) * HID;
#pragma unroll
      for (int n = 0; n < 4; n++) {
        int col = n0 + wn * 64 + n * 16 + lr;
        float v = acc[m][n][j] + b1[e * HID + col];
        float gl = 0.5f * v * (1.0f + erff(v * 0.70710678118654752f));
        hr[col] = f2bf(gl);
      }
    }
  }
}

// ============================================================================
// GEMM2: contrib[slot][t] = h @ w2^T + b2.  128x128, BK=32, 256 thr (4 waves
// 2Mx2N, wave tile 64x64, acc[4][4]).  Grid 8*TMX = 576, 2 blocks/CU.
// ============================================================================
__global__ __launch_bounds__(256, 2) void k_gemm2(
    const ushort_t* __restrict__ hbuf, const float* __restrict__ w2,
    const float* __restrict__ b2,
    const int* __restrict__ assign, const int* __restrict__ cur,
    const int* __restrict__ segoff, const int* __restrict__ blk_e,
    const int* __restrict__ blk_m0, float* __restrict__ contrib) {
  const int nwg = 8 * TMX;                     // 576
  int f = blockIdx.x;
  int lg = (f & 7) * (nwg >> 3) + (f >> 3);
  int m_idx = lg % TMX;                        // m-inner: chunk reuses B-panel
  int n_idx = lg / TMX;
  int e = blk_e[m_idx];
  if (e < 0) return;
  int m0 = blk_m0[m_idx];
  int count = cur[e];
  int n0 = n_idx << 7;
  int so = segoff[e];

  __shared__ __attribute__((aligned(16))) ushort_t A[4][128][32];
  __shared__ __attribute__((aligned(16))) ushort_t Bv[4][128][32];
  int tid = threadIdx.x;
  int lane = tid & 63, wid = tid >> 6;

  int srow = lane >> 2;
  int sunit = ((lane & 3) ^ ((lane >> 3) & 3)) << 3;
  int pA0 = m0 + wid * 16 + srow;
  int pA1 = pA0 + 64;
  int pa0 = (pA0 < count) ? pA0 : (count - 1);
  int pa1 = (pA1 < count) ? pA1 : (count - 1);
  const ushort_t* gA0 = hbuf + (size_t)(so + pa0) * HID + sunit;
  const ushort_t* gA1 = hbuf + (size_t)(so + pa1) * HID + sunit;

  // B staging (reg-transpose from fp32 w2 [H][D])
  int u0 = tid, u1 = tid + 256;
  int nu0 = u0 & 127, ko0 = u0 >> 7;
  int nu1 = u1 & 127, ko1 = u1 >> 7;
  int uo0 = ko0 ^ ((nu0 >> 1) & 3);
  int uo1 = ko1 ^ ((nu1 >> 1) & 3);
  const float* wbase = w2 + (size_t)e * HID * DIM;
  const float* gB0 = wbase + (size_t)(ko0 * 8) * DIM + n0 + nu0;
  const float* gB1 = wbase + (size_t)(ko1 * 8) * DIM + n0 + nu1;
  float brg[2][2][8];

  int wm = wid >> 1, wn = wid & 1;             // wave tile: 64(m) x 64(n)
  int lr = lane & 15, g = lane >> 4;
  int xsw = ((g ^ ((lr >> 1) & 3)) << 3);
  f32x4 acc[4][4];
  f32x4 zero = {0.f, 0.f, 0.f, 0.f};
#pragma unroll
  for (int m = 0; m < 4; m++)
#pragma unroll
    for (int n = 0; n < 4; n++) acc[m][n] = zero;

#define ALOAD2(SL, K0)                                         \
  { GLOAD_LDS16(gA0 + (K0), &A[SL][wid * 16][0]);              \
    GLOAD_LDS16(gA1 + (K0), &A[SL][64 + wid * 16][0]); }
#define BLOAD2(S, KT)                                                          \
  { const float* s0_ = gB0 + (size_t)(KT) * 32 * DIM;                          \
    const float* s1_ = gB1 + (size_t)(KT) * 32 * DIM;                          \
    _Pragma("unroll")                                                          \
    for (int j = 0; j < 8; j++) {                                              \
      brg[S][0][j] = s0_[(size_t)j * DIM];                                     \
      brg[S][1][j] = s1_[(size_t)j * DIM];                                     \
    } }
#define BWRITE2(S, SL)                                                         \
  { short8v p0_, p1_;                                                          \
    _Pragma("unroll")                                                          \
    for (int j = 0; j < 8; j++) {                                              \
      p0_[j] = (short)f2bf(brg[S][0][j]);                                      \
      p1_[j] = (short)f2bf(brg[S][1][j]);                                      \
    }                                                                          \
    *(short8v*)&Bv[SL][nu0][uo0 * 8] = p0_;                                    \
    *(short8v*)&Bv[SL][nu1][uo1 * 8] = p1_; }

#define TILEK2(SL, T, VMX, DOA, DOB, DOW, LS, WS)                               \
  { short8v bv[4], af[4];                                                       \
    _Pragma("unroll")                                                           \
    for (int n = 0; n < 4; n++)                                                 \
      bv[n] = *(const short8v*)&Bv[SL][wn * 64 + n * 16 + lr][xsw];             \
    _Pragma("unroll")                                                           \
    for (int m = 0; m < 4; m++)                                                 \
      af[m] = *(const short8v*)&A[SL][wm * 64 + m * 16 + lr][xsw];              \
    if (DOA) { ALOAD2((((SL) + 3) & 3), ((T) + 3) * 32); }                      \
    if (DOB) { BLOAD2(LS, (T) + 2); }                                           \
    VMX;                                                                        \
    if (DOW) { BWRITE2(WS, (((SL) + 1) & 3)); }                                 \
    LGKM0;                                                                      \
    __builtin_amdgcn_s_barrier();                                               \
    __builtin_amdgcn_sched_barrier(0);                                          \
    __builtin_amdgcn_s_setprio(1);                                              \
    _Pragma("unroll")                                                           \
    for (int m = 0; m < 4; m++)                                                 \
      _Pragma("unroll")                                                         \
      for (int n = 0; n < 4; n++)                                               \
        acc[m][n] = __builtin_amdgcn_mfma_f32_16x16x32_bf16(af[m], bv[n],       \
                                                            acc[m][n], 0, 0, 0);\
    __builtin_amdgcn_s_setprio(0); }

  ALOAD2(0, 0); ALOAD2(1, 32); ALOAD2(2, 64);
  BLOAD2(0, 0); BLOAD2(1, 1);
  VM16;
  BWRITE2(0, 0);
  LGKM0;
  __builtin_amdgcn_s_barrier();
  __builtin_amdgcn_sched_barrier(0);

  const int NT = HID / 32;                     // 128
  for (int t = 0; t < NT - 4; t += 4) {
    TILEK2(0, t + 0, VM18, 1, 1, 1, 0, 1);
    TILEK2(1, t + 1, VM18, 1, 1, 1, 1, 0);
    TILEK2(2, t + 2, VM18, 1, 1, 1, 0, 1);
    TILEK2(3, t + 3, VM18, 1, 1, 1, 1, 0);
  }
  TILEK2(0, NT - 4, VM18, 1, 1, 1, 0, 1);
  TILEK2(1, NT - 3, VM16, 0, 1, 1, 1, 0);
  TILEK2(2, NT - 2, VM0,  0, 0, 1, 0, 1);
  TILEK2(3, NT - 1, VMN,  0, 0, 0, 0, 0);
#undef ALOAD2
#undef BLOAD2
#undef BWRITE2
#undef TILEK2

#pragma unroll
  for (int m = 0; m < 4; m++) {
#pragma unroll
    for (int j = 0; j < 4; j++) {
      int p = m0 + wm * 64 + m * 16 + g * 4 + j;
      if (p >= count) continue;
      int a = assign[e * BT + p];
      int t = a >> 1, slot = a & 1;
      float* cr = contrib + ((size_t)slot * BT + t) * DIM;
#pragma unroll
      for (int n = 0; n < 4; n++) {
        int col = n0 + wn * 64 + n * 16 + lr;
        cr[col] = acc[m][n][j] + b2[e * DIM + col];
      }
    }
  }
}

// -------- combine: final = c0*probs[:,0] + c1*probs[:,1] --------
__global__ void k_combine(const float* __restrict__ contrib,
                          const float* __restrict__ probs01,
                          float* __restrict__ out) {
  int idx = blockIdx.x * blockDim.x + threadIdx.x;
  const int n4 = BT * DIM / 4;
  if (idx >= n4) return;
  int t = idx >> 8;
  float wA = probs01[t * 2 + 0], wB = probs01[t * 2 + 1];
  float4 c0 = ((const float4*)contrib)[idx];
  float4 c1 = ((const float4*)(contrib + (size_t)BT * DIM))[idx];
  float4 o;
  o.x = c0.x * wA + c1.x * wB;
  o.y = c0.y * wA + c1.y * wB;
  o.z = c0.z * wA + c1.z * wB;
  o.w = c0.w * wA + c1.w * wB;
  ((float4*)out)[idx] = o;
}

extern "C" void kernel_launch(void* const* d_in, const int* in_sizes, int n_in,
                              void* d_out, int out_size, void* d_ws, size_t ws_size,
                              hipStream_t stream) {
  const float* x  = (const float*)d_in[0];
  const float* wg = (const float*)d_in[1];
  const float* w1 = (const float*)d_in[2];
  const float* b1 = (const float*)d_in[3];
  const float* w2 = (const float*)d_in[4];
  const float* b2 = (const float*)d_in[5];
  float* out = (float*)d_out;
  float* logits_out = out + (size_t)BT * DIM;

  char* ws = (char*)d_ws;
  size_t off = 0;
  auto alloc = [&](size_t bytes) -> void* {
    void* p = ws + off;
    off = (off + bytes + 255) & ~(size_t)255;
    return p;
  };
  ushort_t* xbf    = (ushort_t*)alloc((size_t)BT * DIM * 2);
  ushort_t* hbuf   = (ushort_t*)alloc((size_t)2 * BT * HID * 2);
  float*    contrib= (float*)alloc((size_t)2 * BT * DIM * 4);
  float*    probs01= (float*)alloc((size_t)BT * 2 * 4);
  int*      assign = (int*)alloc((size_t)NE * BT * 4);
  int*      cur    = (int*)alloc(64);
  int*      segoff = (int*)alloc(64);
  int*      blk2_e = (int*)alloc(TMX2 * 4);
  int*      blk2_m0= (int*)alloc(TMX2 * 4);
  int*      blk_e  = (int*)alloc(TMX * 4);
  int*      blk_m0 = (int*)alloc(TMX * 4);
  if (off > ws_size) return;

  hipMemsetAsync(cur, 0, NE * sizeof(int), stream);
  hipLaunchKernelGGL(k_prep_router, dim3(BT), dim3(256), 0, stream,
                     x, wg, xbf, logits_out, probs01, assign, cur);
  hipLaunchKernelGGL(k_plan, dim3(1), dim3(64), 0, stream, cur, segoff,
                     blk2_e, blk2_m0, blk_e, blk_m0);
  hipLaunchKernelGGL(k_gemm1, dim3(16 * TMX2), dim3(512), 0, stream,
                     xbf, w1, b1, assign, cur, segoff, blk2_e, blk2_m0, hbuf);
  hipLaunchKernelGGL(k_gemm2, dim3(8 * TMX), dim3(256), 0, stream,
                     hbuf, w2, b2, assign, cur, segoff, blk_e, blk_m0, contrib);
  hipLaunchKernelGGL(k_combine, dim3((BT * DIM / 4 + 255) / 256), dim3(256), 0, stream,
                     contrib, probs01, out);
}